// Round 23
// baseline (147.163 us; speedup 1.0000x reference)
//
#include <hip/hip_runtime.h>
#include <math.h>

// ---------------------------------------------------------------------------
// Problem constants
// ---------------------------------------------------------------------------
#define BS     8
#define LL     256
#define JJ     48
#define NN     32
#define TT     48
#define DM     512
#define DEMB   300
#define DFIX   30000
#define DEXT   32000
#define SRC_TOT (LL + JJ + NN)      // 336
#define ROWS   (BS * TT)            // 384
#define NT     470                  // logits n-tiles (470*64 = 30080)
#define KH     320                  // Hh padded K (300 -> 320)

typedef float f32x4  __attribute__((ext_vector_type(4)));
typedef short bf16x8 __attribute__((ext_vector_type(8)));

__device__ __forceinline__ short f2bf(float f) {
    union { float f; unsigned u; } v; v.f = f;
    return (short)((v.u + 0x7FFFu + ((v.u >> 16) & 1u)) >> 16);  // RNE
}
__device__ __forceinline__ float bf2f(short s) {
    union { unsigned u; float f; } v;
    v.u = ((unsigned)(unsigned short)s) << 16;
    return v.f;
}
__device__ __forceinline__ float fast_exp2(float x) {
#if __has_builtin(__builtin_amdgcn_exp2f)
    return __builtin_amdgcn_exp2f(x);
#else
    return exp2f(x);
#endif
}
__device__ __forceinline__ float fast_rcp(float x) {
#if __has_builtin(__builtin_amdgcn_rcpf)
    return __builtin_amdgcn_rcpf(x);
#else
    return 1.f / x;
#endif
}
__device__ __forceinline__ float fast_tanh(float x) {
    x = fminf(fmaxf(x, -15.f), 15.f);
    const float e = fast_exp2(x * 2.885390082f);
    return (e - 1.f) * fast_rcp(e + 1.f);
}
__device__ __forceinline__ bool smask_true(const void* smask, bool byteLayout, int i)
{
    if (byteLayout) return ((const unsigned char*)smask)[i] != 0;
    return ((const int*)smask)[i] != 0;
}
__device__ __forceinline__ void mask8(const void* smask, bool byteLayout, int i,
                                      int* mb)
{
    if (byteLayout) {
        const uchar4 a = ((const uchar4*)((const unsigned char*)smask + i))[0];
        const uchar4 b = ((const uchar4*)((const unsigned char*)smask + i))[1];
        mb[0]=a.x; mb[1]=a.y; mb[2]=a.z; mb[3]=a.w;
        mb[4]=b.x; mb[5]=b.y; mb[6]=b.z; mb[7]=b.w;
    } else {
        const int* p = (const int*)smask + i;
        #pragma unroll
        for (int j = 0; j < 8; ++j) mb[j] = p[j];
    }
}

// async global->LDS, 16B per lane (lds base wave-uniform, gsrc per-lane)
__device__ __forceinline__ void gld_lds16(const short* gsrc, short* ldst)
{
    __builtin_amdgcn_global_load_lds(
        (const __attribute__((address_space(1))) void*)gsrc,
        (__attribute__((address_space(3))) void*)ldst, 16, 0, 0);
}

// ---------------------------------------------------------------------------
// Prep (standalone, 9 KB LDS). Modes: ntx>0 transpose-cast; ntx==0 flat cast;
// ntx==-1 mix-precompute.
// ---------------------------------------------------------------------------
struct PDesc { const float* src; short* dst; int K, N, Kp, ntx, tiles; };
struct PArgs { PDesc d[16]; int nd; const float* Wm; const float* bm; };

__global__ __launch_bounds__(256) void prep_kernel(PArgs pa)
{
    __shared__ short T[64][72];
    int tile = blockIdx.x, g = 0;
    while (g + 1 < pa.nd && tile >= pa.d[g].tiles) { tile -= pa.d[g].tiles; ++g; }
    const PDesc d = pa.d[g];
    const int tid = threadIdx.x;

    if (d.ntx == -1) {                // mix precompute: 4 waves = 4 rows
        const int r = tile * 4 + (tid >> 6);
        const int lane = tid & 63;
        if (r >= d.K) return;
        const int s0 = d.Kp;
        const int woff = (s0 < 0) ? 0 : (s0 == 0) ? 512 : (s0 == 48) ? 1024 : 1536;
        const float4* xp = (const float4*)(d.src + (size_t)r * DM) + lane * 2;
        const float4 x0 = xp[0], x1 = xp[1];
        const float xv[8] = { x0.x, x0.y, x0.z, x0.w, x1.x, x1.y, x1.z, x1.w };
        const float4* wp = (const float4*)(pa.Wm + (size_t)(woff + lane * 8) * 4);
        float acc[4] = {0.f, 0.f, 0.f, 0.f};
        #pragma unroll
        for (int j = 0; j < 8; ++j) {
            const float4 w = wp[j];
            acc[0] = fmaf(xv[j], w.x, acc[0]);
            acc[1] = fmaf(xv[j], w.y, acc[1]);
            acc[2] = fmaf(xv[j], w.z, acc[2]);
            acc[3] = fmaf(xv[j], w.w, acc[3]);
        }
        #pragma unroll
        for (int c = 0; c < 4; ++c)
            #pragma unroll
            for (int o = 32; o; o >>= 1) acc[c] += __shfl_xor(acc[c], o);
        if (lane == 0) {
            float* dst = (float*)d.dst;
            if (s0 < 0) {
                #pragma unroll
                for (int c = 0; c < 4; ++c) dst[r * 4 + c] = acc[c] + pa.bm[c];
            } else {
                const int b = r / d.N, s = r % d.N;
                #pragma unroll
                for (int c = 0; c < 4; ++c)
                    dst[((size_t)b * SRC_TOT + s0 + s) * 4 + c] = acc[c];
            }
        }
        return;
    }

    if (d.ntx == 0) {                 // flat fp32 -> bf16 cast
        const int i = (tile * 256 + tid) * 8;
        if (i < d.K) {
            const float4 a = ((const float4*)(d.src + i))[0];
            const float4 b = ((const float4*)(d.src + i))[1];
            bf16x8 v;
            v[0]=f2bf(a.x); v[1]=f2bf(a.y); v[2]=f2bf(a.z); v[3]=f2bf(a.w);
            v[4]=f2bf(b.x); v[5]=f2bf(b.y); v[6]=f2bf(b.z); v[7]=f2bf(b.w);
            *(bf16x8*)&d.dst[i] = v;
        }
        return;
    }
    const int kt = tile / d.ntx, nt = tile % d.ntx;
    const int k0 = kt * 64, n0 = nt * 64;
    {
        const int n = n0 + (tid & 63);
        #pragma unroll
        for (int p = 0; p < 16; ++p) {
            const int kk = p * 4 + (tid >> 6);
            const int k = k0 + kk;
            float v = 0.f;
            if (k < d.K && n < d.N) v = d.src[(size_t)k * d.N + n];
            T[kk][tid & 63] = f2bf(v);
        }
    }
    __syncthreads();
    {
        const int nn = tid >> 2;
        const int kq = (tid & 3) * 16;
        const int n = n0 + nn;
        if (n < d.N) {
            bf16x8 v0, v1;
            #pragma unroll
            for (int j = 0; j < 8; ++j) v0[j] = T[kq + j][nn];
            #pragma unroll
            for (int j = 0; j < 8; ++j) v1[j] = T[kq + 8 + j][nn];
            *(bf16x8*)&d.dst[(size_t)n * d.Kp + k0 + kq]     = v0;
            *(bf16x8*)&d.dst[(size_t)n * d.Kp + k0 + kq + 8] = v1;
        }
    }
}

// ---------------------------------------------------------------------------
// 128x64-tile bf16-MFMA GEMM, batched, async global_load_lds staging.
// Linear LDS: A entry = kb*128+row (512 entries x 16B), B entry = kb*64+row
// (256 entries x 16B). Per-wave-uniform LDS base + per-lane global source.
// OOB B reads (gA cols>=300, logits cols>=30000) stay in-workspace; their
// acc columns are masked/zeroed in the epilogue.
// obf: 0 fp32 C; 2 bf16 C zero-pad npad; 1 bf16 C + fused softmax partials.
// ---------------------------------------------------------------------------
struct GDesc { const short* A; const short* Bt; const float* bias; void* C;
               const void* smask; float* pstat;
               int M, N, K, Kp, nx, my, obf, npad, nt, tiles; };
struct GArgs { GDesc d[7]; int nd; };

__global__ __launch_bounds__(256) void gemm_bf16_kernel(GArgs ga)
{
    __shared__ short AsLin[2][512][8];   // 16 KB : entry = kb*128 + row
    __shared__ short BsLin[2][256][8];   //  8 KB : entry = kb*64  + row
    __shared__ float pm_s[128][2];
    __shared__ float ps_s[128][2];

    int tile = blockIdx.x, g = 0;
    while (g + 1 < ga.nd && tile >= ga.d[g].tiles) { tile -= ga.d[g].tiles; ++g; }
    const GDesc d = ga.d[g];
    const short* __restrict__ A  = d.A;
    const short* __restrict__ Bt = d.Bt;
    const float* bias = d.bias;
    const int N = d.N, Kp = d.Kp;
    const int nx = d.nx, my = d.my, obf = d.obf, npad = d.npad;

    int bm, bn;
    if (my > 0) { bm = (tile % my) * 128; bn = (tile / my) * 64; }
    else        { bm = (tile / nx) * 128; bn = (tile % nx) * 64; }
    const int tid  = threadIdx.x;
    const int lane = tid & 63;
    const int wv   = tid >> 6;           // wave id (uniform per wave)
    const int wm   = (wv >> 1) * 64;     // 0 or 64
    const int wn   = (wv & 1) * 32;      // 0 or 32

    // staging via async direct-to-LDS
    auto stage = [&](int buf, int k0) {
        #pragma unroll
        for (int p = 0; p < 2; ++p) {
            const int e   = p * 256 + tid;        // 0..511
            const int kb  = e >> 7;               // 0..3
            const int row = e & 127;              // 0..127
            const short* gsrc = &A[(size_t)(bm + row) * Kp + k0 + kb * 8];
            gld_lds16(gsrc, &AsLin[buf][p * 256 + wv * 64][0]);
        }
        {
            const int kb  = tid >> 6;             // 0..3
            const int row = tid & 63;             // 0..63
            const short* gsrc = &Bt[(size_t)(bn + row) * Kp + k0 + kb * 8];
            gld_lds16(gsrc, &BsLin[buf][wv * 64][0]);
        }
    };

    f32x4 acc[4][2] = {};
    const int nk = Kp / 32;

    auto compute = [&](int cur) {
        bf16x8 af[4], bfr[2];
        #pragma unroll
        for (int i = 0; i < 4; ++i) {
            const int e = (lane >> 4) * 128 + wm + i * 16 + (lane & 15);
            af[i] = *(const bf16x8*)&AsLin[cur][e][0];
        }
        #pragma unroll
        for (int j = 0; j < 2; ++j) {
            const int e = (lane >> 4) * 64 + wn + j * 16 + (lane & 15);
            bfr[j] = *(const bf16x8*)&BsLin[cur][e][0];
        }
        #pragma unroll
        for (int mi = 0; mi < 4; ++mi)
            #pragma unroll
            for (int ni = 0; ni < 2; ++ni)
                acc[mi][ni] = __builtin_amdgcn_mfma_f32_16x16x32_bf16(
                    af[mi], bfr[ni], acc[mi][ni], 0, 0, 0);
    };

    stage(0, 0);
    __syncthreads();
    for (int kk = 0; kk < nk; ++kk) {
        const int cur = kk & 1;
        if (kk + 1 < nk) stage(cur ^ 1, (kk + 1) * 32);
        compute(cur);
        __syncthreads();
    }

    if (obf == 0) {
        float* Cf = (float*)d.C;
        #pragma unroll
        for (int ni = 0; ni < 2; ++ni) {
            const int gn = bn + wn + ni * 16 + (lane & 15);
            if (gn >= N) continue;
            const float bb = bias ? bias[gn] : 0.f;
            #pragma unroll
            for (int mi = 0; mi < 4; ++mi)
                #pragma unroll
                for (int r = 0; r < 4; ++r) {
                    const int gm = bm + wm + mi * 16 + (lane >> 4) * 4 + r;
                    Cf[(size_t)gm * N + gn] = acc[mi][ni][r] + bb;
                }
        }
    } else if (obf == 2) {
        short* Cs = (short*)d.C;
        #pragma unroll
        for (int ni = 0; ni < 2; ++ni) {
            const int gn = bn + wn + ni * 16 + (lane & 15);
            if (gn >= npad) continue;
            const bool valid = (gn < N);
            const float bb = (valid && bias) ? bias[gn] : 0.f;
            #pragma unroll
            for (int mi = 0; mi < 4; ++mi)
                #pragma unroll
                for (int r = 0; r < 4; ++r) {
                    const int gm = bm + wm + mi * 16 + (lane >> 4) * 4 + r;
                    Cs[(size_t)gm * npad + gn] = valid ? f2bf(acc[mi][ni][r] + bb) : (short)0;
                }
        }
    } else {
        short* Cs = (short*)d.C;
        const void* sm2 = d.smask;
        const bool byteLayout = (((const int*)sm2)[1] == 0x01010101);
        int mk[2];
        #pragma unroll
        for (int ni = 0; ni < 2; ++ni) {
            const int gn = bn + wn + ni * 16 + (lane & 15);
            const bool inb = (gn < N);
            mk[ni] = inb && smask_true(sm2, byteLayout, inb ? gn : 0);
            if (inb) {
                #pragma unroll
                for (int mi = 0; mi < 4; ++mi)
                    #pragma unroll
                    for (int r = 0; r < 4; ++r) {
                        const int gm = bm + wm + mi * 16 + (lane >> 4) * 4 + r;
                        Cs[(size_t)gm * N + gn] = f2bf(acc[mi][ni][r]);
                    }
            }
        }
        #pragma unroll
        for (int mi = 0; mi < 4; ++mi) {
            #pragma unroll
            for (int r = 0; r < 4; ++r) {
                const int rl = wm + mi * 16 + (lane >> 4) * 4 + r;  // 0..127
                float vmax = -INFINITY;
                #pragma unroll
                for (int ni = 0; ni < 2; ++ni)
                    if (mk[ni]) vmax = fmaxf(vmax, acc[mi][ni][r]);
                #pragma unroll
                for (int o = 1; o < 16; o <<= 1)
                    vmax = fmaxf(vmax, __shfl_xor(vmax, o));
                float se = 0.f;
                #pragma unroll
                for (int ni = 0; ni < 2; ++ni)
                    if (mk[ni]) se += __expf(acc[mi][ni][r] - vmax);
                #pragma unroll
                for (int o = 1; o < 16; o <<= 1)
                    se += __shfl_xor(se, o);
                if ((lane & 15) == 0) {
                    pm_s[rl][wn >> 5] = vmax;
                    ps_s[rl][wn >> 5] = se;
                }
            }
        }
        __syncthreads();
        if (tid < 128) {
            const float mA = pm_s[tid][0], mB = pm_s[tid][1];
            const float sA = ps_s[tid][0], sB = ps_s[tid][1];
            const float m = fmaxf(mA, mB);
            float s = 0.f;
            if (sA > 0.f) s += sA * __expf(mA - m);
            if (sB > 0.f) s += sB * __expf(mB - m);
            float* ps = d.pstat;
            const size_t idx = ((size_t)(bm + tid) * d.nt + (bn >> 6)) * 2;
            ps[idx + 0] = m;
            ps[idx + 1] = s;
        }
    }
}

// ---------------------------------------------------------------------------
// Scores (bf16 K/Q), load-balanced: grid (ROWS, 6 chunks), 0 LDS.
// ---------------------------------------------------------------------------
struct SDesc { const short* Kp; const short* Qp; const float* vv;
               int Sb, s0, cnt, off; };
struct SArgs { SDesc c[6]; };

__global__ __launch_bounds__(256) void scores_kernel(SArgs sa,
                                                     float* __restrict__ scb)
{
    const SDesc d = sa.c[blockIdx.y];
    const int bt   = blockIdx.x;
    const int b    = bt / TT;
    const int tid  = threadIdx.x;
    const int lane = tid & 63;
    const int wave = tid >> 6;

    float qp[8], vv[8];
    {
        const bf16x8 q = *(const bf16x8*)&d.Qp[(size_t)bt * DM + lane * 8];
        #pragma unroll
        for (int j = 0; j < 8; ++j) qp[j] = bf2f(q[j]);
        const float4 a = ((const float4*)(d.vv + lane * 8))[0];
        const float4 c = ((const float4*)(d.vv + lane * 8))[1];
        vv[0]=a.x; vv[1]=a.y; vv[2]=a.z; vv[3]=a.w;
        vv[4]=c.x; vv[5]=c.y; vv[6]=c.z; vv[7]=c.w;
    }
    for (int s = wave; s < d.cnt; s += 4) {
        const bf16x8 kv = *(const bf16x8*)&d.Kp[((size_t)b * d.Sb + d.s0 + s) * DM + lane * 8];
        float acc = 0.f;
        #pragma unroll
        for (int j = 0; j < 8; ++j)
            acc = fmaf(vv[j], fast_tanh(qp[j] + bf2f(kv[j])), acc);
        #pragma unroll
        for (int off = 32; off; off >>= 1) acc += __shfl_xor(acc, off);
        if (lane == 0) scb[(size_t)bt * SRC_TOT + d.off + s] = acc;
    }
}

// ---------------------------------------------------------------------------
// attn2mix v2: softmax(3) + mix via precomputed Vall/base + stats-combine.
// ---------------------------------------------------------------------------
__global__ __launch_bounds__(512) void attn2mix_kernel(
    const float* __restrict__ scb,
    const float* __restrict__ Vall,     // [BS][SRC_TOT][4]
    const float* __restrict__ base,     // [ROWS][4] (incl. bm)
    const float* __restrict__ pstat,
    float* __restrict__ vals, float* __restrict__ stat,
    float* __restrict__ lam_out)
{
    __shared__ float a_sh[SRC_TOT];
    __shared__ float red[16];
    __shared__ float redm[32];
    __shared__ float s_lam[4];
    const int bt   = blockIdx.x;
    const int b    = bt / TT;
    const int tid  = threadIdx.x;
    const int lane = tid & 63;
    const int wave = tid >> 6;
    const float* srow = scb + (size_t)bt * SRC_TOT;

    #pragma unroll
    for (int br = 0; br < 3; ++br) {
        const int off = (br == 0) ? 0 : (br == 1) ? JJ : (JJ + NN);
        const int cnt = (br == 0) ? JJ : (br == 1) ? NN : LL;
        float x = (tid < cnt) ? srow[off + tid] : -INFINITY;
        float m = x;
        #pragma unroll
        for (int o = 32; o; o >>= 1) m = fmaxf(m, __shfl_xor(m, o));
        if (lane == 0) red[wave] = m;
        __syncthreads();
        m = red[0];
        #pragma unroll
        for (int w = 1; w < 8; ++w) m = fmaxf(m, red[w]);
        float e = (tid < cnt) ? __expf(x - m) : 0.f;
        float ss = e;
        #pragma unroll
        for (int o = 32; o; o >>= 1) ss += __shfl_xor(ss, o);
        if (lane == 0) red[8 + wave] = ss;
        __syncthreads();
        float denom = 0.f;
        #pragma unroll
        for (int w = 0; w < 8; ++w) denom += red[8 + w];
        if (tid < cnt) a_sh[off + tid] = e / denom;
        __syncthreads();
    }
    // mix via Vall
    {
        float c0 = 0.f, c1 = 0.f, c2 = 0.f, c3 = 0.f;
        if (tid < SRC_TOT) {
            const float a = a_sh[tid];
            const float4 v = *(const float4*)&Vall[((size_t)b * SRC_TOT + tid) * 4];
            c0 = a * v.x; c1 = a * v.y; c2 = a * v.z; c3 = a * v.w;
        }
        #pragma unroll
        for (int o = 32; o; o >>= 1) {
            c0 += __shfl_xor(c0, o); c1 += __shfl_xor(c1, o);
            c2 += __shfl_xor(c2, o); c3 += __shfl_xor(c3, o);
        }
        if (lane == 0) {
            redm[wave * 4 + 0] = c0; redm[wave * 4 + 1] = c1;
            redm[wave * 4 + 2] = c2; redm[wave * 4 + 3] = c3;
        }
        __syncthreads();
        if (tid == 0) {
            float l[4];
            #pragma unroll
            for (int c = 0; c < 4; ++c) {
                float s = base[bt * 4 + c];
                #pragma unroll
                for (int w = 0; w < 8; ++w) s += redm[w * 4 + c];
                l[c] = s;
            }
            const float mx = fmaxf(fmaxf(l[0], l[1]), fmaxf(l[2], l[3]));
            const float e0 = __expf(l[0] - mx), e1 = __expf(l[1] - mx);
            const float e2 = __expf(l[2] - mx), e3 = __expf(l[3] - mx);
            const float inv = 1.f / (e0 + e1 + e2 + e3);
            s_lam[0] = e0 * inv; s_lam[1] = e1 * inv;
            s_lam[2] = e2 * inv; s_lam[3] = e3 * inv;
            lam_out[bt * 4 + 0] = e0 * inv; lam_out[bt * 4 + 1] = e1 * inv;
            lam_out[bt * 4 + 2] = e2 * inv; lam_out[bt * 4 + 3] = e3 * inv;
        }
    }
    __syncthreads();
    // stats combine (wave 0) -> stat
    if (wave == 0) {
        float m = -INFINITY;
        for (int c = lane; c < NT; c += 64)
            m = fmaxf(m, pstat[((size_t)bt * NT + c) * 2]);
        #pragma unroll
        for (int o = 32; o; o >>= 1) m = fmaxf(m, __shfl_xor(m, o));
        float s = 0.f;
        for (int c = lane; c < NT; c += 64) {
            const float pm = pstat[((size_t)bt * NT + c) * 2];
            const float ps = pstat[((size_t)bt * NT + c) * 2 + 1];
            if (ps > 0.f) s += ps * __expf(pm - m);
        }
        #pragma unroll
        for (int o = 32; o; o >>= 1) s += __shfl_xor(s, o);
        if (lane == 0) {
            stat[bt * 2 + 0] = m;
            stat[bt * 2 + 1] = s_lam[0] / s;
        }
    }
    // lambda-scaled scatter values (source_ext order: [P | Q | QA])
    if (tid < SRC_TOT) {
        float val;
        if      (tid < LL)      val = a_sh[JJ + NN + tid]        * s_lam[3];
        else if (tid < LL + JJ) val = a_sh[tid - LL]             * s_lam[1];
        else                    val = a_sh[JJ + (tid - LL - JJ)] * s_lam[2];
        vals[(size_t)bt * SRC_TOT + tid] = val;
    }
}

// ---------------------------------------------------------------------------
// writescatter: grid (ROWS, 8 chunks) x 256; segment-owned write + scatter.
// ---------------------------------------------------------------------------
__global__ __launch_bounds__(256) void writescatter_kernel(
    const short* __restrict__ logits, const void* __restrict__ smask,
    const float* __restrict__ stat, const float* __restrict__ vals,
    const void* __restrict__ src_ext, float* __restrict__ out)
{
    const bool byteLayout = (((const int*)smask)[1] == 0x01010101);
    const int r  = blockIdx.x;
    const int c0 = blockIdx.y * 4096;
    const float m   = stat[r * 2 + 0];
    const float inv = stat[r * 2 + 1];
    const short* lrow = logits + (size_t)r * DFIX;
    float* orow = out + (size_t)r * DEXT;
    const int tid = threadIdx.x;

    #pragma unroll
    for (int k = 0; k < 2; ++k) {
        const int i = c0 + (k * 256 + tid) * 8;
        if (i >= DEXT) continue;
        float4 o0 = make_float4(0.f, 0.f, 0.f, 0.f);
        float4 o1 = make_float4(0.f, 0.f, 0.f, 0.f);
        if (i < DFIX) {                 // 30000 % 8 == 0: no straddle
            const bf16x8 v = *(const bf16x8*)&lrow[i];
            int mb[8]; mask8(smask, byteLayout, i, mb);
            o0.x = mb[0] ? __expf(bf2f(v[0]) - m) * inv : 0.f;
            o0.y = mb[1] ? __expf(bf2f(v[1]) - m) * inv : 0.f;
            o0.z = mb[2] ? __expf(bf2f(v[2]) - m) * inv : 0.f;
            o0.w = mb[3] ? __expf(bf2f(v[3]) - m) * inv : 0.f;
            o1.x = mb[4] ? __expf(bf2f(v[4]) - m) * inv : 0.f;
            o1.y = mb[5] ? __expf(bf2f(v[5]) - m) * inv : 0.f;
            o1.z = mb[6] ? __expf(bf2f(v[6]) - m) * inv : 0.f;
            o1.w = mb[7] ? __expf(bf2f(v[7]) - m) * inv : 0.f;
        }
        *(float4*)&orow[i]     = o0;
        *(float4*)&orow[i + 4] = o1;
    }
    __syncthreads();
    {
        const int* s32 = (const int*)src_ext;
        const bool src64 = (s32[1] == 0 && s32[3] == 0 && s32[5] == 0 && s32[7] == 0);
        const int b = r / TT;
        for (int p = tid; p < SRC_TOT; p += 256) {
            const int pos = b * SRC_TOT + p;
            const int idx = src64 ? (int)((const long long*)src_ext)[pos] : s32[pos];
            if (idx >= c0 && idx < c0 + 4096)
                atomicAdd(&orow[idx], vals[(size_t)r * SRC_TOT + p]);
        }
    }
}

// ---------------------------------------------------------------------------
extern "C" void kernel_launch(void* const* d_in, const int* in_sizes, int n_in,
                              void* d_out, int out_size, void* d_ws, size_t ws_size,
                              hipStream_t stream)
{
    const float* Mp   = (const float*)d_in[0];
    const float* Mq   = (const float*)d_in[1];
    const float* Mqa  = (const float*)d_in[2];
    const float* Mnlg = (const float*)d_in[3];
    const void* src_ext = d_in[7];
    const void* smask   = d_in[8];
    const float* Wk_q = (const float*)d_in[10];
    const float* bk_q = (const float*)d_in[11];
    const float* Wq_q = (const float*)d_in[12];
    const float* bq_q = (const float*)d_in[13];
    const float* v_q  = (const float*)d_in[14];
    const float* Wk_a = (const float*)d_in[15];
    const float* bk_a = (const float*)d_in[16];
    const float* Wq_a = (const float*)d_in[17];
    const float* bq_a = (const float*)d_in[18];
    const float* v_a  = (const float*)d_in[19];
    const float* Wk_p = (const float*)d_in[20];
    const float* bk_p = (const float*)d_in[21];
    const float* Wq_p = (const float*)d_in[22];
    const float* bq_p = (const float*)d_in[23];
    const float* v_p  = (const float*)d_in[24];
    const float* W1   = (const float*)d_in[25];
    const float* b1   = (const float*)d_in[26];
    const float* W2   = (const float*)d_in[27];
    const float* Wm   = (const float*)d_in[28];
    const float* bm   = (const float*)d_in[29];
    float* out = (float*)d_out;

    char* ws = (char*)d_ws;
    size_t off = 0;
    auto alloc = [&](size_t bytes) -> char* {
        char* p = ws + off;
        off += (bytes + 255) & ~(size_t)255;
        return p;
    };
    short* logits = (short*)alloc((size_t)ROWS * DFIX * 2);
    short* KpP    = (short*)alloc((size_t)BS * LL * DM * 2);
    short* KpQ    = (short*)alloc((size_t)BS * JJ * DM * 2);
    short* KpA    = (short*)alloc((size_t)BS * NN * DM * 2);
    short* QpQ    = (short*)alloc((size_t)ROWS * DM * 2);
    short* QpA    = (short*)alloc((size_t)ROWS * DM * 2);
    short* QpP    = (short*)alloc((size_t)ROWS * DM * 2);
    float* pstat  = (float*)alloc((size_t)ROWS * NT * 2 * 4);
    float* scb    = (float*)alloc((size_t)ROWS * SRC_TOT * 4);
    float* vals   = (float*)alloc((size_t)ROWS * SRC_TOT * 4);
    float* stat   = (float*)alloc((size_t)ROWS * 2 * 4);
    float* Vall   = (float*)alloc((size_t)BS * SRC_TOT * 4 * 4);
    float* baseV  = (float*)alloc((size_t)ROWS * 4 * 4);
    short* tWkq = (short*)alloc((size_t)DM * DM * 2);
    short* tWqq = (short*)alloc((size_t)DM * DM * 2);
    short* tWka = (short*)alloc((size_t)DM * DM * 2);
    short* tWqa = (short*)alloc((size_t)DM * DM * 2);
    short* tWkp = (short*)alloc((size_t)DM * DM * 2);
    short* tWqp = (short*)alloc((size_t)DM * DM * 2);
    short* tW1  = (short*)alloc((size_t)DEMB * DM * 2);
    short* tW2  = (short*)alloc((size_t)DFIX * KH * 2);
    short* Mp_bf   = (short*)alloc((size_t)BS * LL * DM * 2);
    short* Mq_bf   = (short*)alloc((size_t)BS * JJ * DM * 2);
    short* Mqa_bf  = (short*)alloc((size_t)BS * NN * DM * 2);
    short* Mnlg_bf = (short*)alloc((size_t)ROWS * DM * 2);
    short* Hh_bf   = (short*)alloc((size_t)ROWS * KH * 2);
    (void)ws_size; (void)in_sizes; (void)n_in; (void)out_size;

    // ---- L1: all prep (transpose-cast, flat casts, mix precompute)
    PArgs p1;
    p1.nd = 16;
    p1.Wm = Wm; p1.bm = bm;
    p1.d[0]  = { Wk_p, tWkp, DM,   DM,   DM, 8, 64 };
    p1.d[1]  = { Wk_q, tWkq, DM,   DM,   DM, 8, 64 };
    p1.d[2]  = { Wk_a, tWka, DM,   DM,   DM, 8, 64 };
    p1.d[3]  = { Wq_q, tWqq, DM,   DM,   DM, 8, 64 };
    p1.d[4]  = { Wq_a, tWqa, DM,   DM,   DM, 8, 64 };
    p1.d[5]  = { Wq_p, tWqp, DM,   DM,   DM, 8, 64 };
    p1.d[6]  = { W1,   tW1,  DM,   DEMB, DM, 5, 40 };
    p1.d[7]  = { W2,   tW2,  DEMB, DFIX, KH, 469, 2345 };
    p1.d[8]  = { Mp,   Mp_bf,   BS*LL*DM, 0, 0, 0, (BS*LL*DM) / 2048 };
    p1.d[9]  = { Mq,   Mq_bf,   BS*JJ*DM, 0, 0, 0, (BS*JJ*DM) / 2048 };
    p1.d[10] = { Mqa,  Mqa_bf,  BS*NN*DM, 0, 0, 0, (BS*NN*DM) / 2048 };
    p1.d[11] = { Mnlg, Mnlg_bf, ROWS*DM,  0, 0, 0, (ROWS*DM) / 2048 };
    p1.d[12] = { Mnlg, (short*)baseV, ROWS,  0,  -1, -1,  96 };
    p1.d[13] = { Mq,   (short*)Vall,  BS*JJ, JJ,  0, -1,  96 };
    p1.d[14] = { Mqa,  (short*)Vall,  BS*NN, NN, 48, -1,  64 };
    p1.d[15] = { Mp,   (short*)Vall,  BS*LL, LL, 80, -1, 512 };
    prep_kernel<<<64*6 + 40 + 2345 + 512 + 96 + 64 + 96 + 96 + 96 + 64 + 512,
                  256, 0, stream>>>(p1);

    // ---- L2: gA = Mnlg @ W1 + b1 -> Hh_bf (128x64 tiles, 15 blocks)
    GArgs g2;
    g2.nd = 1;
    g2.d[0] = { Mnlg_bf, tW1, b1, Hh_bf, nullptr, nullptr,
                ROWS, DEMB, DM, DM, 5, 0, 2, KH, 0, 15 };   // 3 m x 5 n
    gemm_bf16_kernel<<<15, 256, 0, stream>>>(g2);

    // ---- L3: projections (long-K first) + logits (fused stats) last
    GArgs g3;
    g3.nd = 7;
    g3.d[0] = { Mp_bf,   tWkp, bk_p, KpP, nullptr, nullptr,
                BS*LL, DM, DM, DM, 8, 0, 2, DM, 0, 128 };   // 16 m x 8 n
    g3.d[1] = { Mq_bf,   tWkq, bk_q, KpQ, nullptr, nullptr,
                BS*JJ, DM, DM, DM, 8, 0, 2, DM, 0, 24 };
    g3.d[2] = { Mqa_bf,  tWka, bk_a, KpA, nullptr, nullptr,
                BS*NN, DM, DM, DM, 8, 0, 2, DM, 0, 16 };
    g3.d[3] = { Mnlg_bf, tWqq, bq_q, QpQ, nullptr, nullptr,
                ROWS, DM, DM, DM, 8, 0, 2, DM, 0, 24 };
    g3.d[4] = { Mnlg_bf, tWqa, bq_a, QpA, nullptr, nullptr,
                ROWS, DM, DM, DM, 8, 0, 2, DM, 0, 24 };
    g3.d[5] = { Mnlg_bf, tWqp, bq_p, QpP, nullptr, nullptr,
                ROWS, DM, DM, DM, 8, 0, 2, DM, 0, 24 };
    g3.d[6] = { Hh_bf,   tW2,  nullptr, logits, smask, pstat,
                ROWS, DFIX, DEMB, KH, 0, 3, 1, DFIX, NT, 1410 };  // 3 m x 470 n
    gemm_bf16_kernel<<<128 + 24 + 16 + 24 * 3 + 1410, 256, 0, stream>>>(g3);

    // ---- L4: scores
    SArgs sa;
    sa.c[0] = { KpQ, QpQ, v_q, JJ,   0, JJ,  0 };
    sa.c[1] = { KpA, QpA, v_a, NN,   0, NN,  JJ };
    sa.c[2] = { KpP, QpP, v_p, LL,   0, 64,  JJ + NN };
    sa.c[3] = { KpP, QpP, v_p, LL,  64, 64,  JJ + NN + 64 };
    sa.c[4] = { KpP, QpP, v_p, LL, 128, 64,  JJ + NN + 128 };
    sa.c[5] = { KpP, QpP, v_p, LL, 192, 64,  JJ + NN + 192 };
    scores_kernel<<<dim3(ROWS, 6), 256, 0, stream>>>(sa, scb);

    // ---- L5: attn2mix v2 (softmax + mix-via-Vall + combine)
    attn2mix_kernel<<<ROWS, 512, 0, stream>>>(
        scb, Vall, baseV, pstat, vals, stat, out + (size_t)ROWS * DEXT);

    // ---- L6: chunked write + in-segment scatter
    writescatter_kernel<<<dim3(ROWS, 8), 256, 0, stream>>>(
        logits, smask, stat, vals, src_ext, out);
}

// Round 24
// 131.594 us; speedup vs baseline: 1.1183x; 1.1183x over previous
//
#include <hip/hip_runtime.h>
#include <math.h>

// ---------------------------------------------------------------------------
// Problem constants
// ---------------------------------------------------------------------------
#define BS     8
#define LL     256
#define JJ     48
#define NN     32
#define TT     48
#define DM     512
#define DEMB   300
#define DFIX   30000
#define DEXT   32000
#define SRC_TOT (LL + JJ + NN)      // 336
#define ROWS   (BS * TT)            // 384
#define NT     470                  // logits n-tiles (470*64 = 30080)
#define KH     320                  // Hh padded K (300 -> 320)

typedef float f32x4  __attribute__((ext_vector_type(4)));
typedef short bf16x8 __attribute__((ext_vector_type(8)));

__device__ __forceinline__ short f2bf(float f) {
    union { float f; unsigned u; } v; v.f = f;
    return (short)((v.u + 0x7FFFu + ((v.u >> 16) & 1u)) >> 16);  // RNE
}
__device__ __forceinline__ float bf2f(short s) {
    union { unsigned u; float f; } v;
    v.u = ((unsigned)(unsigned short)s) << 16;
    return v.f;
}
__device__ __forceinline__ float fast_exp2(float x) {
#if __has_builtin(__builtin_amdgcn_exp2f)
    return __builtin_amdgcn_exp2f(x);
#else
    return exp2f(x);
#endif
}
__device__ __forceinline__ float fast_rcp(float x) {
#if __has_builtin(__builtin_amdgcn_rcpf)
    return __builtin_amdgcn_rcpf(x);
#else
    return 1.f / x;
#endif
}
__device__ __forceinline__ float fast_tanh(float x) {
    x = fminf(fmaxf(x, -15.f), 15.f);
    const float e = fast_exp2(x * 2.885390082f);
    return (e - 1.f) * fast_rcp(e + 1.f);
}
__device__ __forceinline__ bool smask_true(const void* smask, bool byteLayout, int i)
{
    if (byteLayout) return ((const unsigned char*)smask)[i] != 0;
    return ((const int*)smask)[i] != 0;
}
__device__ __forceinline__ void mask8(const void* smask, bool byteLayout, int i,
                                      int* mb)
{
    if (byteLayout) {
        const uchar4 a = ((const uchar4*)((const unsigned char*)smask + i))[0];
        const uchar4 b = ((const uchar4*)((const unsigned char*)smask + i))[1];
        mb[0]=a.x; mb[1]=a.y; mb[2]=a.z; mb[3]=a.w;
        mb[4]=b.x; mb[5]=b.y; mb[6]=b.z; mb[7]=b.w;
    } else {
        const int* p = (const int*)smask + i;
        #pragma unroll
        for (int j = 0; j < 8; ++j) mb[j] = p[j];
    }
}

// ---------------------------------------------------------------------------
// Prep (standalone, 9 KB LDS). Modes: ntx>0 transpose-cast; ntx==0 flat cast;
// ntx==-1 mix-precompute.
// ---------------------------------------------------------------------------
struct PDesc { const float* src; short* dst; int K, N, Kp, ntx, tiles; };
struct PArgs { PDesc d[16]; int nd; const float* Wm; const float* bm; };

__global__ __launch_bounds__(256) void prep_kernel(PArgs pa)
{
    __shared__ short T[64][72];
    int tile = blockIdx.x, g = 0;
    while (g + 1 < pa.nd && tile >= pa.d[g].tiles) { tile -= pa.d[g].tiles; ++g; }
    const PDesc d = pa.d[g];
    const int tid = threadIdx.x;

    if (d.ntx == -1) {                // mix precompute: 4 waves = 4 rows
        const int r = tile * 4 + (tid >> 6);
        const int lane = tid & 63;
        if (r >= d.K) return;
        const int s0 = d.Kp;
        const int woff = (s0 < 0) ? 0 : (s0 == 0) ? 512 : (s0 == 48) ? 1024 : 1536;
        const float4* xp = (const float4*)(d.src + (size_t)r * DM) + lane * 2;
        const float4 x0 = xp[0], x1 = xp[1];
        const float xv[8] = { x0.x, x0.y, x0.z, x0.w, x1.x, x1.y, x1.z, x1.w };
        const float4* wp = (const float4*)(pa.Wm + (size_t)(woff + lane * 8) * 4);
        float acc[4] = {0.f, 0.f, 0.f, 0.f};
        #pragma unroll
        for (int j = 0; j < 8; ++j) {
            const float4 w = wp[j];
            acc[0] = fmaf(xv[j], w.x, acc[0]);
            acc[1] = fmaf(xv[j], w.y, acc[1]);
            acc[2] = fmaf(xv[j], w.z, acc[2]);
            acc[3] = fmaf(xv[j], w.w, acc[3]);
        }
        #pragma unroll
        for (int c = 0; c < 4; ++c)
            #pragma unroll
            for (int o = 32; o; o >>= 1) acc[c] += __shfl_xor(acc[c], o);
        if (lane == 0) {
            float* dst = (float*)d.dst;
            if (s0 < 0) {
                #pragma unroll
                for (int c = 0; c < 4; ++c) dst[r * 4 + c] = acc[c] + pa.bm[c];
            } else {
                const int b = r / d.N, s = r % d.N;
                #pragma unroll
                for (int c = 0; c < 4; ++c)
                    dst[((size_t)b * SRC_TOT + s0 + s) * 4 + c] = acc[c];
            }
        }
        return;
    }

    if (d.ntx == 0) {                 // flat fp32 -> bf16 cast
        const int i = (tile * 256 + tid) * 8;
        if (i < d.K) {
            const float4 a = ((const float4*)(d.src + i))[0];
            const float4 b = ((const float4*)(d.src + i))[1];
            bf16x8 v;
            v[0]=f2bf(a.x); v[1]=f2bf(a.y); v[2]=f2bf(a.z); v[3]=f2bf(a.w);
            v[4]=f2bf(b.x); v[5]=f2bf(b.y); v[6]=f2bf(b.z); v[7]=f2bf(b.w);
            *(bf16x8*)&d.dst[i] = v;
        }
        return;
    }
    const int kt = tile / d.ntx, nt = tile % d.ntx;
    const int k0 = kt * 64, n0 = nt * 64;
    {
        const int n = n0 + (tid & 63);
        #pragma unroll
        for (int p = 0; p < 16; ++p) {
            const int kk = p * 4 + (tid >> 6);
            const int k = k0 + kk;
            float v = 0.f;
            if (k < d.K && n < d.N) v = d.src[(size_t)k * d.N + n];
            T[kk][tid & 63] = f2bf(v);
        }
    }
    __syncthreads();
    {
        const int nn = tid >> 2;
        const int kq = (tid & 3) * 16;
        const int n = n0 + nn;
        if (n < d.N) {
            bf16x8 v0, v1;
            #pragma unroll
            for (int j = 0; j < 8; ++j) v0[j] = T[kq + j][nn];
            #pragma unroll
            for (int j = 0; j < 8; ++j) v1[j] = T[kq + 8 + j][nn];
            *(bf16x8*)&d.dst[(size_t)n * d.Kp + k0 + kq]     = v0;
            *(bf16x8*)&d.dst[(size_t)n * d.Kp + k0 + kq + 8] = v1;
        }
    }
}

// ---------------------------------------------------------------------------
// 128x64-tile bf16-MFMA GEMM, batched, prefetch depth 2 with STATIC register
// sets (ra0/ra1, rb0/rb1; K-loop unrolled by 2, all indices literal).
// nk is even for all descriptors (16/16/10). obf: 0 fp32 C; 2 bf16 C
// zero-pad npad; 1 bf16 C + fused masked softmax partials.
// ---------------------------------------------------------------------------
struct GDesc { const short* A; const short* Bt; const float* bias; void* C;
               const void* smask; float* pstat;
               int M, N, K, Kp, nx, my, obf, npad, nt, tiles; };
struct GArgs { GDesc d[7]; int nd; };

__global__ __launch_bounds__(256) void gemm_bf16_kernel(GArgs ga)
{
    __shared__ short As[2][4][130][8];   // 128 rows (pad 130)
    __shared__ short Bs[2][4][66][8];    // 64 rows (pad 66)
    __shared__ float pm_s[128][2];
    __shared__ float ps_s[128][2];

    int tile = blockIdx.x, g = 0;
    while (g + 1 < ga.nd && tile >= ga.d[g].tiles) { tile -= ga.d[g].tiles; ++g; }
    const GDesc d = ga.d[g];
    const short* __restrict__ A  = d.A;
    const short* __restrict__ Bt = d.Bt;
    const float* bias = d.bias;
    const int N = d.N, Kp = d.Kp;
    const int nx = d.nx, my = d.my, obf = d.obf, npad = d.npad;

    int bm, bn;
    if (my > 0) { bm = (tile % my) * 128; bn = (tile / my) * 64; }
    else        { bm = (tile / nx) * 128; bn = (tile % nx) * 64; }
    const int tid  = threadIdx.x;
    const int lane = tid & 63;
    const int wv   = tid >> 6;
    const int wm   = (wv >> 1) * 64;     // 0 or 64
    const int wn   = (wv & 1) * 32;      // 0 or 32

    bf16x8 ra0[2], ra1[2], rb0, rb1;     // named sets, static indexing only

    auto loadAto = [&](bf16x8 (&r)[2], int k0) {
        #pragma unroll
        for (int p = 0; p < 2; ++p) {
            const int row = p * 64 + (tid >> 2);
            r[p] = *(const bf16x8*)&A[(size_t)(bm + row) * Kp + k0 + (tid & 3) * 8];
        }
    };
    auto loadBto = [&](bf16x8& r, int k0) {
        const int n = tid >> 2, kb = tid & 3;
        const int gn = bn + n;
        bf16x8 v = {};
        if (gn < N) v = *(const bf16x8*)&Bt[(size_t)gn * Kp + k0 + kb * 8];
        r = v;
    };
    auto storeAfrom = [&](int buf, const bf16x8 (&r)[2]) {
        const int kb = tid & 3;
        #pragma unroll
        for (int p = 0; p < 2; ++p)
            *(bf16x8*)&As[buf][kb][p * 64 + (tid >> 2)][0] = r[p];
    };
    auto storeBfrom = [&](int buf, const bf16x8& r) {
        const int n = tid >> 2, kb = tid & 3;
        *(bf16x8*)&Bs[buf][kb][n][0] = r;
    };

    f32x4 acc[4][2] = {};
    const int nk = Kp / 32;              // even for all descs

    auto compute = [&](int cur) {
        bf16x8 af[4], bfr[2];
        #pragma unroll
        for (int i = 0; i < 4; ++i)
            af[i]  = *(const bf16x8*)&As[cur][lane >> 4][wm + i * 16 + (lane & 15)][0];
        #pragma unroll
        for (int j = 0; j < 2; ++j)
            bfr[j] = *(const bf16x8*)&Bs[cur][lane >> 4][wn + j * 16 + (lane & 15)][0];
        #pragma unroll
        for (int mi = 0; mi < 4; ++mi)
            #pragma unroll
            for (int ni = 0; ni < 2; ++ni)
                acc[mi][ni] = __builtin_amdgcn_mfma_f32_16x16x32_bf16(
                    af[mi], bfr[ni], acc[mi][ni], 0, 0, 0);
    };

    // prologue: k0 staged to buf0; k1 in flight in set1
    loadAto(ra0, 0); loadBto(rb0, 0);
    storeAfrom(0, ra0); storeBfrom(0, rb0);
    if (nk > 1) { loadAto(ra1, 32); loadBto(rb1, 32); }
    __syncthreads();

    for (int kk = 0; kk < nk; kk += 2) {
        // even step: compute buf0 (k = kk); issue k+2 into set0; store k+1
        if (kk + 2 < nk) { loadAto(ra0, (kk + 2) * 32); loadBto(rb0, (kk + 2) * 32); }
        compute(0);
        if (kk + 1 < nk) { storeAfrom(1, ra1); storeBfrom(1, rb1); }
        __syncthreads();
        // odd step: compute buf1 (k = kk+1); issue k+3 into set1; store k+2
        if (kk + 1 < nk) {
            if (kk + 3 < nk) { loadAto(ra1, (kk + 3) * 32); loadBto(rb1, (kk + 3) * 32); }
            compute(1);
            if (kk + 2 < nk) { storeAfrom(0, ra0); storeBfrom(0, rb0); }
            __syncthreads();
        }
    }

    if (obf == 0) {
        float* Cf = (float*)d.C;
        #pragma unroll
        for (int ni = 0; ni < 2; ++ni) {
            const int gn = bn + wn + ni * 16 + (lane & 15);
            if (gn >= N) continue;
            const float bb = bias ? bias[gn] : 0.f;
            #pragma unroll
            for (int mi = 0; mi < 4; ++mi)
                #pragma unroll
                for (int r = 0; r < 4; ++r) {
                    const int gm = bm + wm + mi * 16 + (lane >> 4) * 4 + r;
                    Cf[(size_t)gm * N + gn] = acc[mi][ni][r] + bb;
                }
        }
    } else if (obf == 2) {
        short* Cs = (short*)d.C;
        #pragma unroll
        for (int ni = 0; ni < 2; ++ni) {
            const int gn = bn + wn + ni * 16 + (lane & 15);
            if (gn >= npad) continue;
            const bool valid = (gn < N);
            const float bb = (valid && bias) ? bias[gn] : 0.f;
            #pragma unroll
            for (int mi = 0; mi < 4; ++mi)
                #pragma unroll
                for (int r = 0; r < 4; ++r) {
                    const int gm = bm + wm + mi * 16 + (lane >> 4) * 4 + r;
                    Cs[(size_t)gm * npad + gn] = valid ? f2bf(acc[mi][ni][r] + bb) : (short)0;
                }
        }
    } else {
        short* Cs = (short*)d.C;
        const void* sm2 = d.smask;
        const bool byteLayout = (((const int*)sm2)[1] == 0x01010101);
        int mk[2];
        #pragma unroll
        for (int ni = 0; ni < 2; ++ni) {
            const int gn = bn + wn + ni * 16 + (lane & 15);
            const bool inb = (gn < N);
            mk[ni] = inb && smask_true(sm2, byteLayout, inb ? gn : 0);
            if (inb) {
                #pragma unroll
                for (int mi = 0; mi < 4; ++mi)
                    #pragma unroll
                    for (int r = 0; r < 4; ++r) {
                        const int gm = bm + wm + mi * 16 + (lane >> 4) * 4 + r;
                        Cs[(size_t)gm * N + gn] = f2bf(acc[mi][ni][r]);
                    }
            }
        }
        #pragma unroll
        for (int mi = 0; mi < 4; ++mi) {
            #pragma unroll
            for (int r = 0; r < 4; ++r) {
                const int rl = wm + mi * 16 + (lane >> 4) * 4 + r;  // 0..127
                float vmax = -INFINITY;
                #pragma unroll
                for (int ni = 0; ni < 2; ++ni)
                    if (mk[ni]) vmax = fmaxf(vmax, acc[mi][ni][r]);
                #pragma unroll
                for (int o = 1; o < 16; o <<= 1)
                    vmax = fmaxf(vmax, __shfl_xor(vmax, o));
                float se = 0.f;
                #pragma unroll
                for (int ni = 0; ni < 2; ++ni)
                    if (mk[ni]) se += __expf(acc[mi][ni][r] - vmax);
                #pragma unroll
                for (int o = 1; o < 16; o <<= 1)
                    se += __shfl_xor(se, o);
                if ((lane & 15) == 0) {
                    pm_s[rl][wn >> 5] = vmax;
                    ps_s[rl][wn >> 5] = se;
                }
            }
        }
        __syncthreads();
        if (tid < 128) {
            const float mA = pm_s[tid][0], mB = pm_s[tid][1];
            const float sA = ps_s[tid][0], sB = ps_s[tid][1];
            const float m = fmaxf(mA, mB);
            float s = 0.f;
            if (sA > 0.f) s += sA * __expf(mA - m);
            if (sB > 0.f) s += sB * __expf(mB - m);
            float* ps = d.pstat;
            const size_t idx = ((size_t)(bm + tid) * d.nt + (bn >> 6)) * 2;
            ps[idx + 0] = m;
            ps[idx + 1] = s;
        }
    }
}

// ---------------------------------------------------------------------------
// Scores (bf16 K/Q), load-balanced: grid (ROWS, 6 chunks), 0 LDS.
// ---------------------------------------------------------------------------
struct SDesc { const short* Kp; const short* Qp; const float* vv;
               int Sb, s0, cnt, off; };
struct SArgs { SDesc c[6]; };

__global__ __launch_bounds__(256) void scores_kernel(SArgs sa,
                                                     float* __restrict__ scb)
{
    const SDesc d = sa.c[blockIdx.y];
    const int bt   = blockIdx.x;
    const int b    = bt / TT;
    const int tid  = threadIdx.x;
    const int lane = tid & 63;
    const int wave = tid >> 6;

    float qp[8], vv[8];
    {
        const bf16x8 q = *(const bf16x8*)&d.Qp[(size_t)bt * DM + lane * 8];
        #pragma unroll
        for (int j = 0; j < 8; ++j) qp[j] = bf2f(q[j]);
        const float4 a = ((const float4*)(d.vv + lane * 8))[0];
        const float4 c = ((const float4*)(d.vv + lane * 8))[1];
        vv[0]=a.x; vv[1]=a.y; vv[2]=a.z; vv[3]=a.w;
        vv[4]=c.x; vv[5]=c.y; vv[6]=c.z; vv[7]=c.w;
    }
    for (int s = wave; s < d.cnt; s += 4) {
        const bf16x8 kv = *(const bf16x8*)&d.Kp[((size_t)b * d.Sb + d.s0 + s) * DM + lane * 8];
        float acc = 0.f;
        #pragma unroll
        for (int j = 0; j < 8; ++j)
            acc = fmaf(vv[j], fast_tanh(qp[j] + bf2f(kv[j])), acc);
        #pragma unroll
        for (int off = 32; off; off >>= 1) acc += __shfl_xor(acc, off);
        if (lane == 0) scb[(size_t)bt * SRC_TOT + d.off + s] = acc;
    }
}

// ---------------------------------------------------------------------------
// attn2mix v2: softmax(3) + mix via precomputed Vall/base + stats-combine.
// ---------------------------------------------------------------------------
__global__ __launch_bounds__(512) void attn2mix_kernel(
    const float* __restrict__ scb,
    const float* __restrict__ Vall,     // [BS][SRC_TOT][4]
    const float* __restrict__ base,     // [ROWS][4] (incl. bm)
    const float* __restrict__ pstat,
    float* __restrict__ vals, float* __restrict__ stat,
    float* __restrict__ lam_out)
{
    __shared__ float a_sh[SRC_TOT];
    __shared__ float red[16];
    __shared__ float redm[32];
    __shared__ float s_lam[4];
    const int bt   = blockIdx.x;
    const int b    = bt / TT;
    const int tid  = threadIdx.x;
    const int lane = tid & 63;
    const int wave = tid >> 6;
    const float* srow = scb + (size_t)bt * SRC_TOT;

    #pragma unroll
    for (int br = 0; br < 3; ++br) {
        const int off = (br == 0) ? 0 : (br == 1) ? JJ : (JJ + NN);
        const int cnt = (br == 0) ? JJ : (br == 1) ? NN : LL;
        float x = (tid < cnt) ? srow[off + tid] : -INFINITY;
        float m = x;
        #pragma unroll
        for (int o = 32; o; o >>= 1) m = fmaxf(m, __shfl_xor(m, o));
        if (lane == 0) red[wave] = m;
        __syncthreads();
        m = red[0];
        #pragma unroll
        for (int w = 1; w < 8; ++w) m = fmaxf(m, red[w]);
        float e = (tid < cnt) ? __expf(x - m) : 0.f;
        float ss = e;
        #pragma unroll
        for (int o = 32; o; o >>= 1) ss += __shfl_xor(ss, o);
        if (lane == 0) red[8 + wave] = ss;
        __syncthreads();
        float denom = 0.f;
        #pragma unroll
        for (int w = 0; w < 8; ++w) denom += red[8 + w];
        if (tid < cnt) a_sh[off + tid] = e / denom;
        __syncthreads();
    }
    // mix via Vall
    {
        float c0 = 0.f, c1 = 0.f, c2 = 0.f, c3 = 0.f;
        if (tid < SRC_TOT) {
            const float a = a_sh[tid];
            const float4 v = *(const float4*)&Vall[((size_t)b * SRC_TOT + tid) * 4];
            c0 = a * v.x; c1 = a * v.y; c2 = a * v.z; c3 = a * v.w;
        }
        #pragma unroll
        for (int o = 32; o; o >>= 1) {
            c0 += __shfl_xor(c0, o); c1 += __shfl_xor(c1, o);
            c2 += __shfl_xor(c2, o); c3 += __shfl_xor(c3, o);
        }
        if (lane == 0) {
            redm[wave * 4 + 0] = c0; redm[wave * 4 + 1] = c1;
            redm[wave * 4 + 2] = c2; redm[wave * 4 + 3] = c3;
        }
        __syncthreads();
        if (tid == 0) {
            float l[4];
            #pragma unroll
            for (int c = 0; c < 4; ++c) {
                float s = base[bt * 4 + c];
                #pragma unroll
                for (int w = 0; w < 8; ++w) s += redm[w * 4 + c];
                l[c] = s;
            }
            const float mx = fmaxf(fmaxf(l[0], l[1]), fmaxf(l[2], l[3]));
            const float e0 = __expf(l[0] - mx), e1 = __expf(l[1] - mx);
            const float e2 = __expf(l[2] - mx), e3 = __expf(l[3] - mx);
            const float inv = 1.f / (e0 + e1 + e2 + e3);
            s_lam[0] = e0 * inv; s_lam[1] = e1 * inv;
            s_lam[2] = e2 * inv; s_lam[3] = e3 * inv;
            lam_out[bt * 4 + 0] = e0 * inv; lam_out[bt * 4 + 1] = e1 * inv;
            lam_out[bt * 4 + 2] = e2 * inv; lam_out[bt * 4 + 3] = e3 * inv;
        }
    }
    __syncthreads();
    // stats combine (wave 0) -> stat
    if (wave == 0) {
        float m = -INFINITY;
        for (int c = lane; c < NT; c += 64)
            m = fmaxf(m, pstat[((size_t)bt * NT + c) * 2]);
        #pragma unroll
        for (int o = 32; o; o >>= 1) m = fmaxf(m, __shfl_xor(m, o));
        float s = 0.f;
        for (int c = lane; c < NT; c += 64) {
            const float pm = pstat[((size_t)bt * NT + c) * 2];
            const float ps = pstat[((size_t)bt * NT + c) * 2 + 1];
            if (ps > 0.f) s += ps * __expf(pm - m);
        }
        #pragma unroll
        for (int o = 32; o; o >>= 1) s += __shfl_xor(s, o);
        if (lane == 0) {
            stat[bt * 2 + 0] = m;
            stat[bt * 2 + 1] = s_lam[0] / s;
        }
    }
    // lambda-scaled scatter values (source_ext order: [P | Q | QA])
    if (tid < SRC_TOT) {
        float val;
        if      (tid < LL)      val = a_sh[JJ + NN + tid]        * s_lam[3];
        else if (tid < LL + JJ) val = a_sh[tid - LL]             * s_lam[1];
        else                    val = a_sh[JJ + (tid - LL - JJ)] * s_lam[2];
        vals[(size_t)bt * SRC_TOT + tid] = val;
    }
}

// ---------------------------------------------------------------------------
// writescatter: grid (ROWS, 8 chunks) x 256; segment-owned write + scatter.
// ---------------------------------------------------------------------------
__global__ __launch_bounds__(256) void writescatter_kernel(
    const short* __restrict__ logits, const void* __restrict__ smask,
    const float* __restrict__ stat, const float* __restrict__ vals,
    const void* __restrict__ src_ext, float* __restrict__ out)
{
    const bool byteLayout = (((const int*)smask)[1] == 0x01010101);
    const int r  = blockIdx.x;
    const int c0 = blockIdx.y * 4096;
    const float m   = stat[r * 2 + 0];
    const float inv = stat[r * 2 + 1];
    const short* lrow = logits + (size_t)r * DFIX;
    float* orow = out + (size_t)r * DEXT;
    const int tid = threadIdx.x;

    #pragma unroll
    for (int k = 0; k < 2; ++k) {
        const int i = c0 + (k * 256 + tid) * 8;
        if (i >= DEXT) continue;
        float4 o0 = make_float4(0.f, 0.f, 0.f, 0.f);
        float4 o1 = make_float4(0.f, 0.f, 0.f, 0.f);
        if (i < DFIX) {                 // 30000 % 8 == 0: no straddle
            const bf16x8 v = *(const bf16x8*)&lrow[i];
            int mb[8]; mask8(smask, byteLayout, i, mb);
            o0.x = mb[0] ? __expf(bf2f(v[0]) - m) * inv : 0.f;
            o0.y = mb[1] ? __expf(bf2f(v[1]) - m) * inv : 0.f;
            o0.z = mb[2] ? __expf(bf2f(v[2]) - m) * inv : 0.f;
            o0.w = mb[3] ? __expf(bf2f(v[3]) - m) * inv : 0.f;
            o1.x = mb[4] ? __expf(bf2f(v[4]) - m) * inv : 0.f;
            o1.y = mb[5] ? __expf(bf2f(v[5]) - m) * inv : 0.f;
            o1.z = mb[6] ? __expf(bf2f(v[6]) - m) * inv : 0.f;
            o1.w = mb[7] ? __expf(bf2f(v[7]) - m) * inv : 0.f;
        }
        *(float4*)&orow[i]     = o0;
        *(float4*)&orow[i + 4] = o1;
    }
    __syncthreads();
    {
        const int* s32 = (const int*)src_ext;
        const bool src64 = (s32[1] == 0 && s32[3] == 0 && s32[5] == 0 && s32[7] == 0);
        const int b = r / TT;
        for (int p = tid; p < SRC_TOT; p += 256) {
            const int pos = b * SRC_TOT + p;
            const int idx = src64 ? (int)((const long long*)src_ext)[pos] : s32[pos];
            if (idx >= c0 && idx < c0 + 4096)
                atomicAdd(&orow[idx], vals[(size_t)r * SRC_TOT + p]);
        }
    }
}

// ---------------------------------------------------------------------------
extern "C" void kernel_launch(void* const* d_in, const int* in_sizes, int n_in,
                              void* d_out, int out_size, void* d_ws, size_t ws_size,
                              hipStream_t stream)
{
    const float* Mp   = (const float*)d_in[0];
    const float* Mq   = (const float*)d_in[1];
    const float* Mqa  = (const float*)d_in[2];
    const float* Mnlg = (const float*)d_in[3];
    const void* src_ext = d_in[7];
    const void* smask   = d_in[8];
    const float* Wk_q = (const float*)d_in[10];
    const float* bk_q = (const float*)d_in[11];
    const float* Wq_q = (const float*)d_in[12];
    const float* bq_q = (const float*)d_in[13];
    const float* v_q  = (const float*)d_in[14];
    const float* Wk_a = (const float*)d_in[15];
    const float* bk_a = (const float*)d_in[16];
    const float* Wq_a = (const float*)d_in[17];
    const float* bq_a = (const float*)d_in[18];
    const float* v_a  = (const float*)d_in[19];
    const float* Wk_p = (const float*)d_in[20];
    const float* bk_p = (const float*)d_in[21];
    const float* Wq_p = (const float*)d_in[22];
    const float* bq_p = (const float*)d_in[23];
    const float* v_p  = (const float*)d_in[24];
    const float* W1   = (const float*)d_in[25];
    const float* b1   = (const float*)d_in[26];
    const float* W2   = (const float*)d_in[27];
    const float* Wm   = (const float*)d_in[28];
    const float* bm   = (const float*)d_in[29];
    float* out = (float*)d_out;

    char* ws = (char*)d_ws;
    size_t off = 0;
    auto alloc = [&](size_t bytes) -> char* {
        char* p = ws + off;
        off += (bytes + 255) & ~(size_t)255;
        return p;
    };
    short* logits = (short*)alloc((size_t)ROWS * DFIX * 2);
    short* KpP    = (short*)alloc((size_t)BS * LL * DM * 2);
    short* KpQ    = (short*)alloc((size_t)BS * JJ * DM * 2);
    short* KpA    = (short*)alloc((size_t)BS * NN * DM * 2);
    short* QpQ    = (short*)alloc((size_t)ROWS * DM * 2);
    short* QpA    = (short*)alloc((size_t)ROWS * DM * 2);
    short* QpP    = (short*)alloc((size_t)ROWS * DM * 2);
    float* pstat  = (float*)alloc((size_t)ROWS * NT * 2 * 4);
    float* scb    = (float*)alloc((size_t)ROWS * SRC_TOT * 4);
    float* vals   = (float*)alloc((size_t)ROWS * SRC_TOT * 4);
    float* stat   = (float*)alloc((size_t)ROWS * 2 * 4);
    float* Vall   = (float*)alloc((size_t)BS * SRC_TOT * 4 * 4);
    float* baseV  = (float*)alloc((size_t)ROWS * 4 * 4);
    short* tWkq = (short*)alloc((size_t)DM * DM * 2);
    short* tWqq = (short*)alloc((size_t)DM * DM * 2);
    short* tWka = (short*)alloc((size_t)DM * DM * 2);
    short* tWqa = (short*)alloc((size_t)DM * DM * 2);
    short* tWkp = (short*)alloc((size_t)DM * DM * 2);
    short* tWqp = (short*)alloc((size_t)DM * DM * 2);
    short* tW1  = (short*)alloc((size_t)DEMB * DM * 2);
    short* tW2  = (short*)alloc((size_t)DFIX * KH * 2);
    short* Mp_bf   = (short*)alloc((size_t)BS * LL * DM * 2);
    short* Mq_bf   = (short*)alloc((size_t)BS * JJ * DM * 2);
    short* Mqa_bf  = (short*)alloc((size_t)BS * NN * DM * 2);
    short* Mnlg_bf = (short*)alloc((size_t)ROWS * DM * 2);
    short* Hh_bf   = (short*)alloc((size_t)ROWS * KH * 2);
    (void)ws_size; (void)in_sizes; (void)n_in; (void)out_size;

    // ---- L1: all prep (transpose-cast, flat casts, mix precompute)
    PArgs p1;
    p1.nd = 16;
    p1.Wm = Wm; p1.bm = bm;
    p1.d[0]  = { Wk_p, tWkp, DM,   DM,   DM, 8, 64 };
    p1.d[1]  = { Wk_q, tWkq, DM,   DM,   DM, 8, 64 };
    p1.d[2]  = { Wk_a, tWka, DM,   DM,   DM, 8, 64 };
    p1.d[3]  = { Wq_q, tWqq, DM,   DM,   DM, 8, 64 };
    p1.d[4]  = { Wq_a, tWqa, DM,   DM,   DM, 8, 64 };
    p1.d[5]  = { Wq_p, tWqp, DM,   DM,   DM, 8, 64 };
    p1.d[6]  = { W1,   tW1,  DM,   DEMB, DM, 5, 40 };
    p1.d[7]  = { W2,   tW2,  DEMB, DFIX, KH, 469, 2345 };
    p1.d[8]  = { Mp,   Mp_bf,   BS*LL*DM, 0, 0, 0, (BS*LL*DM) / 2048 };
    p1.d[9]  = { Mq,   Mq_bf,   BS*JJ*DM, 0, 0, 0, (BS*JJ*DM) / 2048 };
    p1.d[10] = { Mqa,  Mqa_bf,  BS*NN*DM, 0, 0, 0, (BS*NN*DM) / 2048 };
    p1.d[11] = { Mnlg, Mnlg_bf, ROWS*DM,  0, 0, 0, (ROWS*DM) / 2048 };
    p1.d[12] = { Mnlg, (short*)baseV, ROWS,  0,  -1, -1,  96 };
    p1.d[13] = { Mq,   (short*)Vall,  BS*JJ, JJ,  0, -1,  96 };
    p1.d[14] = { Mqa,  (short*)Vall,  BS*NN, NN, 48, -1,  64 };
    p1.d[15] = { Mp,   (short*)Vall,  BS*LL, LL, 80, -1, 512 };
    prep_kernel<<<64*6 + 40 + 2345 + 512 + 96 + 64 + 96 + 96 + 96 + 64 + 512,
                  256, 0, stream>>>(p1);

    // ---- L2: gA = Mnlg @ W1 + b1 -> Hh_bf (128x64 tiles, 15 blocks)
    GArgs g2;
    g2.nd = 1;
    g2.d[0] = { Mnlg_bf, tW1, b1, Hh_bf, nullptr, nullptr,
                ROWS, DEMB, DM, DM, 5, 0, 2, KH, 0, 15 };   // 3 m x 5 n
    gemm_bf16_kernel<<<15, 256, 0, stream>>>(g2);

    // ---- L3: projections (long-K first) + logits (fused stats) last
    GArgs g3;
    g3.nd = 7;
    g3.d[0] = { Mp_bf,   tWkp, bk_p, KpP, nullptr, nullptr,
                BS*LL, DM, DM, DM, 8, 0, 2, DM, 0, 128 };   // 16 m x 8 n
    g3.d[1] = { Mq_bf,   tWkq, bk_q, KpQ, nullptr, nullptr,
                BS*JJ, DM, DM, DM, 8, 0, 2, DM, 0, 24 };
    g3.d[2] = { Mqa_bf,  tWka, bk_a, KpA, nullptr, nullptr,
                BS*NN, DM, DM, DM, 8, 0, 2, DM, 0, 16 };
    g3.d[3] = { Mnlg_bf, tWqq, bq_q, QpQ, nullptr, nullptr,
                ROWS, DM, DM, DM, 8, 0, 2, DM, 0, 24 };
    g3.d[4] = { Mnlg_bf, tWqa, bq_a, QpA, nullptr, nullptr,
                ROWS, DM, DM, DM, 8, 0, 2, DM, 0, 24 };
    g3.d[5] = { Mnlg_bf, tWqp, bq_p, QpP, nullptr, nullptr,
                ROWS, DM, DM, DM, 8, 0, 2, DM, 0, 24 };
    g3.d[6] = { Hh_bf,   tW2,  nullptr, logits, smask, pstat,
                ROWS, DFIX, DEMB, KH, 0, 3, 1, DFIX, NT, 1410 };  // 3 m x 470 n
    gemm_bf16_kernel<<<128 + 24 + 16 + 24 * 3 + 1410, 256, 0, stream>>>(g3);

    // ---- L4: scores
    SArgs sa;
    sa.c[0] = { KpQ, QpQ, v_q, JJ,   0, JJ,  0 };
    sa.c[1] = { KpA, QpA, v_a, NN,   0, NN,  JJ };
    sa.c[2] = { KpP, QpP, v_p, LL,   0, 64,  JJ + NN };
    sa.c[3] = { KpP, QpP, v_p, LL,  64, 64,  JJ + NN + 64 };
    sa.c[4] = { KpP, QpP, v_p, LL, 128, 64,  JJ + NN + 128 };
    sa.c[5] = { KpP, QpP, v_p, LL, 192, 64,  JJ + NN + 192 };
    scores_kernel<<<dim3(ROWS, 6), 256, 0, stream>>>(sa, scb);

    // ---- L5: attn2mix v2 (softmax + mix-via-Vall + combine)
    attn2mix_kernel<<<ROWS, 512, 0, stream>>>(
        scb, Vall, baseV, pstat, vals, stat, out + (size_t)ROWS * DEXT);

    // ---- L6: chunked write + in-segment scatter
    writescatter_kernel<<<dim3(ROWS, 8), 256, 0, stream>>>(
        logits, smask, stat, vals, src_ext, out);
}